// Round 13
// baseline (113.307 us; speedup 1.0000x reference)
//
#include <hip/hip_runtime.h>

using short8 = __attribute__((ext_vector_type(8))) short;
using f32x4  = __attribute__((ext_vector_type(4))) float;
using f32x16 = __attribute__((ext_vector_type(16))) float;

typedef const __attribute__((address_space(1))) void* as1cv;
typedef __attribute__((address_space(3))) void* as3v;

__device__ __forceinline__ unsigned short f2bf(float f) {
  unsigned u = __float_as_uint(f);
  u += 0x7fffu + ((u >> 16) & 1u);
  return (unsigned short)(u >> 16);
}

// ---------------- Transpose f32 [rows][cols] -> bf16 [cols][rows] (for W) ----------------
__global__ __launch_bounds__(256) void transpose_f2b_kernel(const float* __restrict__ in,
                                                            unsigned short* __restrict__ out,
                                                            int rows, int cols) {
  __shared__ float tile[32][33];
  const int r0 = blockIdx.x * 32, c0 = blockIdx.y * 32;
  const int li = threadIdx.x >> 5, ci = threadIdx.x & 31;
#pragma unroll
  for (int p = 0; p < 4; ++p) {
    int r = li + p * 8;
    tile[r][ci] = in[(size_t)(r0 + r) * cols + c0 + ci];
  }
  __syncthreads();
#pragma unroll
  for (int p = 0; p < 4; ++p) {
    int c = li + p * 8;
    out[(size_t)(c0 + c) * rows + r0 + ci] = f2bf(tile[ci][c]);
  }
}

// ---------------- adj int32 -> bitmask [2048][64] words ----------------
__global__ __launch_bounds__(256) void adjmask_kernel(const int* __restrict__ adj,
                                                      unsigned* __restrict__ adjm) {
  const int wv = (blockIdx.x << 2) + (threadIdx.x >> 6);
  const int lane = threadIdx.x & 63;
  const int row = wv >> 5, j0 = (wv & 31) << 6;
  unsigned long long mask = __ballot(adj[(size_t)row * 2048 + j0 + lane] > 0);
  if (lane == 0) {
    adjm[row * 64 + (j0 >> 5)]     = (unsigned)mask;
    adjm[row * 64 + (j0 >> 5) + 1] = (unsigned)(mask >> 32);
  }
}

// ---------------- Kernel B: fused conv + Wh GEMM + pack + f1/f2 ----------------
// block: 32 gemm rows = (b, n in [jg*32, jg*32+32)); 512 thr = 8 waves (2 rg x 4 cg).
// whp[b][jc 128][ct 12][lane 64][8]: lane l elem e = Wh[b][jc*16 + (l>>5)*8 + e][ct*32 + (l&31)]
__global__ __launch_bounds__(512) void gemm_wh3_kernel(const float* __restrict__ x,
                                                       const float* __restrict__ cw,
                                                       const float* __restrict__ cb,
                                                       const unsigned short* __restrict__ Wt,
                                                       const float* __restrict__ a,
                                                       unsigned short* __restrict__ whp,
                                                       float* __restrict__ f1,
                                                       float* __restrict__ f2) {
  __shared__ __align__(16) char lds[49344 + 1792 + 256];
  float* xin = (float*)lds;                                   // [12][1028], 1026 used
  unsigned short* atile = (unsigned short*)lds;               // [32][392] (after conv)
  unsigned short* wtile = (unsigned short*)(lds + 25088);     // [32][392]
  float* cws = (float*)(lds + 49344);                         // 432
  float* cbs = cws + 448;                                     // 12
  float* s1s = (float*)(lds + 49344 + 1792);                  // 32
  float* s2s = s1s + 32;                                      // 32

  const int tid = threadIdx.x;
  const int rb = blockIdx.x;
  const int b = rb >> 6, jg = rb & 63;
  const int r0 = rb << 5;
  const int w = tid >> 6, lane = tid & 63;
  const int rg = w >> 2, cg = w & 3;
  const int il = lane & 15, kg = lane >> 4;

  // stage conv weights + x tile
  if (tid < 432) cws[tid] = cw[tid];
  if (tid < 12) cbs[tid] = cb[tid];
  if (tid < 32) { s1s[tid] = 0.f; s2s[tid] = 0.f; }
  const float* xb = x + (size_t)b * 2048 * 12 * 32;
#pragma unroll
  for (int t = 0; t < 12; ++t) {
    for (int i = tid; i < 1026; i += 512) {
      const int gp = jg * 1024 + i - 1;
      float v = 0.f;
      if ((unsigned)gp < 65536u) v = xb[((size_t)(gp >> 5) * 12 + t) * 32 + (gp & 31)];
      xin[t * 1028 + i] = v;
    }
  }
  __syncthreads();

  // conv: each thread 2 p's x 12 t_o
  const int ploc = tid * 2;
  float accv0[12], accv1[12];
#pragma unroll
  for (int to = 0; to < 12; ++to) { accv0[to] = cbs[to]; accv1[to] = cbs[to]; }
#pragma unroll
  for (int ti = 0; ti < 12; ++ti) {
    const float x0 = xin[ti * 1028 + ploc];
    const float x1 = xin[ti * 1028 + ploc + 1];
    const float x2 = xin[ti * 1028 + ploc + 2];
    const float x3 = xin[ti * 1028 + ploc + 3];
#pragma unroll
    for (int to = 0; to < 12; ++to) {
      const float* wp = &cws[(to * 12 + ti) * 3];
      const float w0 = wp[0], w1 = wp[1], w2 = wp[2];
      accv0[to] += x0 * w0 + x1 * w1 + x2 * w2;
      accv1[to] += x1 * w0 + x2 * w1 + x3 * w2;
    }
  }
  __syncthreads();   // all xin reads done before atile overwrite

  // write conv out as bf16 A-tile (atile overlaps xin space)
  {
    const int row = ploc >> 5, f = ploc & 31;
    unsigned* ap32 = (unsigned*)(atile + row * 392 + f);
#pragma unroll
    for (int to = 0; to < 12; ++to) {
      const unsigned lo = f2bf(accv0[to]), hi = f2bf(accv1[to]);
      ap32[to * 16] = lo | (hi << 16);
    }
  }
  __syncthreads();

  // MFMA: 32x384 = A(32x384) @ W(384x384), waves: rg rows-16, cg cols-96
  f32x4 acc[6];
#pragma unroll
  for (int t = 0; t < 6; ++t) acc[t] = (f32x4){0.f, 0.f, 0.f, 0.f};
  const unsigned short* arow = atile + (rg * 16 + il) * 392 + kg * 8;
#pragma unroll
  for (int kk = 0; kk < 12; ++kk) {
    short8 af = *reinterpret_cast<const short8*>(arow + kk * 32);
#pragma unroll
    for (int t = 0; t < 6; ++t) {
      const int c = cg * 96 + t * 16 + il;
      short8 bf = *reinterpret_cast<const short8*>(Wt + (size_t)c * 384 + kk * 32 + kg * 8);
      acc[t] = __builtin_amdgcn_mfma_f32_16x16x32_bf16(af, bf, acc[t], 0, 0, 0);
    }
  }
  // fused f1/f2
  float p1[4] = {0.f, 0.f, 0.f, 0.f}, p2[4] = {0.f, 0.f, 0.f, 0.f};
#pragma unroll
  for (int t = 0; t < 6; ++t) {
    const int c = cg * 96 + t * 16 + il;
    const float a1v = a[c], a2v = a[384 + c];
#pragma unroll
    for (int r = 0; r < 4; ++r) { p1[r] += acc[t][r] * a1v; p2[r] += acc[t][r] * a2v; }
  }
#pragma unroll
  for (int off = 1; off < 16; off <<= 1) {
#pragma unroll
    for (int r = 0; r < 4; ++r) { p1[r] += __shfl_xor(p1[r], off); p2[r] += __shfl_xor(p2[r], off); }
  }
  if (il == 0) {
#pragma unroll
    for (int r = 0; r < 4; ++r) {
      atomicAdd(&s1s[rg * 16 + kg * 4 + r], p1[r]);
      atomicAdd(&s2s[rg * 16 + kg * 4 + r], p2[r]);
    }
  }
#pragma unroll
  for (int t = 0; t < 6; ++t)
#pragma unroll
    for (int r = 0; r < 4; ++r)
      wtile[(rg * 16 + kg * 4 + r) * 392 + cg * 96 + t * 16 + il] = f2bf(acc[t][r]);
  __syncthreads();

  // pack B-frag tiles: 24 tiles (jh 2 x ct 12) x 64 lanes; layout [b][jc][ct]
#pragma unroll
  for (int rep = 0; rep < 3; ++rep) {
    const int flat = rep * 512 + tid;
    const int tile = flat >> 6, l = flat & 63;
    const int ct = tile >> 1, jh = tile & 1;
    const int l5 = l & 31, hw2 = l >> 5;
    short8 v;
#pragma unroll
    for (int e = 0; e < 8; ++e)
      v[e] = (short)wtile[(jh * 16 + hw2 * 8 + e) * 392 + ct * 32 + l5];
    *reinterpret_cast<short8*>((char*)whp +
        ((((size_t)b * 128 + jg * 2 + jh) * 12 + ct) << 10) + l * 16) = v;
  }
  if (tid < 32) { f1[r0 + tid] = s1s[tid]; f2[r0 + tid] = s2s[tid]; }
}

// ---------------- per-batch max of f2 + e2f2 table ----------------
__global__ __launch_bounds__(256) void f2max_kernel(const float* __restrict__ f2,
                                                    float* __restrict__ gmax,
                                                    float* __restrict__ e2f2) {
  __shared__ float wm[4];
  const int b = blockIdx.x;
  const int tid = threadIdx.x;
  float m = -3.0e38f;
  for (int i = tid; i < 2048; i += 256) {
    const float v = f2[b * 2048 + i];
    m = fmaxf(m, v);
    float2 w; w.x = __expf(v); w.y = __expf(0.2f * v);
    *reinterpret_cast<float2*>(e2f2 + (size_t)(b * 2048 + i) * 2) = w;
  }
#pragma unroll
  for (int off = 32; off; off >>= 1) m = fmaxf(m, __shfl_xor(m, off));
  if ((tid & 63) == 0) wm[tid >> 6] = m;
  __syncthreads();
  if (tid == 0) gmax[b] = fmaxf(fmaxf(wm[0], wm[1]), fmaxf(wm[2], wm[3]));
}

// ---------------- Kernel E: attention v9 — LDS-staged 2-phase, cooperative P, no redundancy ----------------
// grid 256: b=(bi&7)>>1 (XCD-local Wh panel), rowgroup=(bi>>3)*2+(bi&1) -> 32 rows.
// 4 waves; wave w owns cols [w*96, w*96+96). K-chunk = 64 j (4 jc), whp blob 48 KB contiguous,
// staged via global_load_lds; P-tile (32x64) computed cooperatively (8 thr/row, separable exp)
// into A-frag LDS. One __syncthreads per chunk, double-buffered.
#define BBYTES 49152
__global__ __launch_bounds__(256) void attn9_kernel(const float* __restrict__ f1,
                                                    const float* __restrict__ e2f2,
                                                    const unsigned* __restrict__ adjm,
                                                    const unsigned short* __restrict__ whp,
                                                    const float* __restrict__ gmax,
                                                    float* __restrict__ out) {
  __shared__ __align__(16) char lds[2 * BBYTES + 2 * 4096 + 128];
  char* pbase = lds + 2 * BBYTES;
  float* dsum = (float*)(lds + 2 * BBYTES + 2 * 4096);

  const int bi = blockIdx.x;
  const int b  = (bi & 7) >> 1;
  const int i0 = (((bi >> 3) << 1) | (bi & 1)) << 5;
  const int tid = threadIdx.x;
  const int wv = tid >> 6, lane = tid & 63;
  const int l5 = lane & 31;

  // P-gen role: row + k-half
  const int prow = tid & 31;           // row 0..31
  const int khalf = tid >> 5;          // 0..7 : k = khalf*8 .. +8
  const int kf = khalf >> 1, hw2 = khalf & 1;
  const int ig = i0 + prow;

  const float* e2f2b = e2f2 + (size_t)b * 2048 * 2;
  const unsigned* adjr = adjm + (size_t)ig * 64;
  const float f1v = f1[b * 2048 + ig];
  const float gm = gmax[b];
  const float mz = f1v + gm;
  const float m  = fmaxf(mz, 0.2f * mz);     // >= true masked row max
  const float E1 = __expf(f1v - m);
  const float F1 = __expf(0.2f * f1v - m);
  const float T  = __expf(-f1v);             // z>0  <=>  exp(f2) > T
  float dloc = 0.f;

  if (tid < 32) dsum[tid] = 0.f;

  const char* whpb = (const char*)whp + (((size_t)b * 128 * 12) << 10);
  char* pwaddr = pbase /*+cur*4096*/ + kf * 1024 + (hw2 * 32 + prow) * 16;

  // stage: 12 x global_load_lds(16B)/thread; blob (chunk) = 48 KB contiguous
#define STAGE(CUR, CHUNK)                                                               \
  { const char* src_ = whpb + (size_t)(CHUNK) * BBYTES + tid * 16;                      \
    char* dst_ = lds + (CUR) * BBYTES + tid * 16;                                       \
    _Pragma("unroll")                                                                   \
    for (int s_ = 0; s_ < 12; ++s_)                                                     \
      __builtin_amdgcn_global_load_lds((as1cv)(const void*)(src_ + s_ * 4096),          \
                                       (as3v)(void*)(dst_ + s_ * 4096), 16, 0, 0); }

  // cooperative P-gen: this thread's (row, 8 j) -> one 16B A-frag blob
#define PGEN(CUR, CHUNK)                                                                \
  { const int j0_ = (CHUNK) * 64 + khalf * 8;                                           \
    const float4* ep_ = (const float4*)(e2f2b + (size_t)j0_ * 2);                       \
    const float4 q0_ = ep_[0], q1_ = ep_[1], q2_ = ep_[2], q3_ = ep_[3];                \
    const unsigned wrd_ = adjr[(CHUNK) * 2 + (khalf >> 2)];                             \
    const unsigned bits_ = (wrd_ >> ((khalf & 3) * 8)) & 0xffu;                         \
    float pv_[8];                                                                       \
    pv_[0] = (q0_.x > T) ? q0_.x * E1 : q0_.y * F1;                                     \
    pv_[1] = (q0_.z > T) ? q0_.z * E1 : q0_.w * F1;                                     \
    pv_[2] = (q1_.x > T) ? q1_.x * E1 : q1_.y * F1;                                     \
    pv_[3] = (q1_.z > T) ? q1_.z * E1 : q1_.w * F1;                                     \
    pv_[4] = (q2_.x > T) ? q2_.x * E1 : q2_.y * F1;                                     \
    pv_[5] = (q2_.z > T) ? q2_.z * E1 : q2_.w * F1;                                     \
    pv_[6] = (q3_.x > T) ? q3_.x * E1 : q3_.y * F1;                                     \
    pv_[7] = (q3_.z > T) ? q3_.z * E1 : q3_.w * F1;                                     \
    unsigned pk_[8];                                                                    \
    float ds_ = 0.f;                                                                    \
    _Pragma("unroll")                                                                   \
    for (int e_ = 0; e_ < 8; ++e_) {                                                    \
      float v_ = ((bits_ >> e_) & 1u) ? pv_[e_] : 0.f;                                  \
      unsigned r_ = (__float_as_uint(v_) + 0x8000u) & 0xffff0000u;                      \
      ds_ += __uint_as_float(r_);                                                       \
      pk_[e_] = r_;                                                                     \
    }                                                                                   \
    dloc += ds_;                                                                        \
    uint4 blob_;                                                                        \
    blob_.x = pk_[1] | (pk_[0] >> 16);                                                  \
    blob_.y = pk_[3] | (pk_[2] >> 16);                                                  \
    blob_.z = pk_[5] | (pk_[4] >> 16);                                                  \
    blob_.w = pk_[7] | (pk_[6] >> 16);                                                  \
    *(uint4*)(pwaddr + (CUR) * 4096) = blob_; }

  const f32x16 zero16 = {0.f,0.f,0.f,0.f,0.f,0.f,0.f,0.f,0.f,0.f,0.f,0.f,0.f,0.f,0.f,0.f};
  f32x16 acc0 = zero16, acc1 = zero16, acc2 = zero16;

  STAGE(0, 0)
  PGEN(0, 0)
  __syncthreads();

  int cur = 0;
  for (int t = 0; t < 32; ++t) {
    if (t < 31) {
      STAGE(cur ^ 1, t + 1)
      PGEN(cur ^ 1, t + 1)
    }
    const char* bb = lds + cur * BBYTES;
    const char* pb = pbase + cur * 4096;
    short8 af0 = *(const short8*)(pb + lane * 16);
    short8 af1 = *(const short8*)(pb + 1024 + lane * 16);
    short8 af2 = *(const short8*)(pb + 2048 + lane * 16);
    short8 af3 = *(const short8*)(pb + 3072 + lane * 16);
    const char* bw = bb + (wv * 3) * 1024 + lane * 16;
    {
      short8 bf0 = *(const short8*)(bw);
      short8 bf1 = *(const short8*)(bw + 12288);
      short8 bf2 = *(const short8*)(bw + 24576);
      short8 bf3 = *(const short8*)(bw + 36864);
      acc0 = __builtin_amdgcn_mfma_f32_32x32x16_bf16(af0, bf0, acc0, 0, 0, 0);
      acc0 = __builtin_amdgcn_mfma_f32_32x32x16_bf16(af1, bf1, acc0, 0, 0, 0);
      acc0 = __builtin_amdgcn_mfma_f32_32x32x16_bf16(af2, bf2, acc0, 0, 0, 0);
      acc0 = __builtin_amdgcn_mfma_f32_32x32x16_bf16(af3, bf3, acc0, 0, 0, 0);
    }
    {
      short8 bf0 = *(const short8*)(bw + 1024);
      short8 bf1 = *(const short8*)(bw + 12288 + 1024);
      short8 bf2 = *(const short8*)(bw + 24576 + 1024);
      short8 bf3 = *(const short8*)(bw + 36864 + 1024);
      acc1 = __builtin_amdgcn_mfma_f32_32x32x16_bf16(af0, bf0, acc1, 0, 0, 0);
      acc1 = __builtin_amdgcn_mfma_f32_32x32x16_bf16(af1, bf1, acc1, 0, 0, 0);
      acc1 = __builtin_amdgcn_mfma_f32_32x32x16_bf16(af2, bf2, acc1, 0, 0, 0);
      acc1 = __builtin_amdgcn_mfma_f32_32x32x16_bf16(af3, bf3, acc1, 0, 0, 0);
    }
    {
      short8 bf0 = *(const short8*)(bw + 2048);
      short8 bf1 = *(const short8*)(bw + 12288 + 2048);
      short8 bf2 = *(const short8*)(bw + 24576 + 2048);
      short8 bf3 = *(const short8*)(bw + 36864 + 2048);
      acc2 = __builtin_amdgcn_mfma_f32_32x32x16_bf16(af0, bf0, acc2, 0, 0, 0);
      acc2 = __builtin_amdgcn_mfma_f32_32x32x16_bf16(af1, bf1, acc2, 0, 0, 0);
      acc2 = __builtin_amdgcn_mfma_f32_32x32x16_bf16(af2, bf2, acc2, 0, 0, 0);
      acc2 = __builtin_amdgcn_mfma_f32_32x32x16_bf16(af3, bf3, acc2, 0, 0, 0);
    }
    __syncthreads();
    cur ^= 1;
  }
#undef STAGE
#undef PGEN

  // ---- epilogue: row denominators via LDS, normalize, elu, store ----
  atomicAdd(&dsum[prow], dloc);
  __syncthreads();

  const int hw = lane >> 5;
  const size_t ob = ((size_t)b * 2048 + i0) * 384 + wv * 96;
#define OUTACC(ACCV, CT3)                                                               \
  _Pragma("unroll")                                                                     \
  for (int q = 0; q < 16; ++q) {                                                        \
    const int row = (q & 3) + 8 * (q >> 2) + 4 * hw;                                    \
    float v = ACCV[q] / dsum[row];                                                      \
    v = v > 0.f ? v : expm1f(v);                                                        \
    out[ob + (size_t)row * 384 + (CT3) * 32 + l5] = v;                                  \
  }
  OUTACC(acc0, 0)
  OUTACC(acc1, 1)
  OUTACC(acc2, 2)
#undef OUTACC
}

extern "C" void kernel_launch(void* const* d_in, const int* in_sizes, int n_in,
                              void* d_out, int out_size, void* d_ws, size_t ws_size,
                              hipStream_t stream) {
  const float* x  = (const float*)d_in[0];
  const int* adj  = (const int*)d_in[1];
  const float* W  = (const float*)d_in[2];
  const float* a  = (const float*)d_in[3];
  const float* cw = (const float*)d_in[4];
  const float* cb = (const float*)d_in[5];
  float* out = (float*)d_out;

  char* ws = (char*)d_ws;
  unsigned short* Wt  = (unsigned short*)ws; ws += (size_t)147456 * 2;   // [384][384] bf16 (T)
  unsigned short* whp = (unsigned short*)ws; ws += (size_t)3145728 * 2;  // packed B-frags [b][jc][ct]
  float* f1           = (float*)ws;          ws += (size_t)8192 * 4;
  float* f2           = (float*)ws;          ws += (size_t)8192 * 4;
  unsigned* adjm      = (unsigned*)ws;       ws += (size_t)2048 * 64 * 4;
  float* gmax         = (float*)ws;          ws += 64;
  float* e2f2         = (float*)ws;          ws += (size_t)8192 * 2 * 4; // [b][j][2]

  transpose_f2b_kernel<<<dim3(12, 12), 256, 0, stream>>>(W, Wt, 384, 384);
  adjmask_kernel<<<dim3(16384), 256, 0, stream>>>(adj, adjm);
  gemm_wh3_kernel<<<dim3(256), 512, 0, stream>>>(x, cw, cb, Wt, a, whp, f1, f2);
  f2max_kernel<<<dim3(4), 256, 0, stream>>>(f2, gmax, e2f2);
  attn9_kernel<<<dim3(256), 256, 0, stream>>>(f1, e2f2, adjm, whp, gmax, out);
}

// Round 17
// 101.683 us; speedup vs baseline: 1.1143x; 1.1143x over previous
//
#include <hip/hip_runtime.h>

using short8 = __attribute__((ext_vector_type(8))) short;
using f32x4  = __attribute__((ext_vector_type(4))) float;
using f32x16 = __attribute__((ext_vector_type(16))) float;

__device__ __forceinline__ unsigned short f2bf(float f) {
  unsigned u = __float_as_uint(f);
  u += 0x7fffu + ((u >> 16) & 1u);
  return (unsigned short)(u >> 16);
}

// ---------------- Transpose f32 [rows][cols] -> bf16 [cols][rows] (for W) ----------------
__global__ __launch_bounds__(256) void transpose_f2b_kernel(const float* __restrict__ in,
                                                            unsigned short* __restrict__ out,
                                                            int rows, int cols) {
  __shared__ float tile[32][33];
  const int r0 = blockIdx.x * 32, c0 = blockIdx.y * 32;
  const int li = threadIdx.x >> 5, ci = threadIdx.x & 31;
#pragma unroll
  for (int p = 0; p < 4; ++p) {
    int r = li + p * 8;
    tile[r][ci] = in[(size_t)(r0 + r) * cols + c0 + ci];
  }
  __syncthreads();
#pragma unroll
  for (int p = 0; p < 4; ++p) {
    int c = li + p * 8;
    out[(size_t)(c0 + c) * rows + r0 + ci] = f2bf(tile[ci][c]);
  }
}

// ---------------- adj int32 -> bitmask [2048][64] words ----------------
__global__ __launch_bounds__(256) void adjmask_kernel(const int* __restrict__ adj,
                                                      unsigned* __restrict__ adjm) {
  const int wv = (blockIdx.x << 2) + (threadIdx.x >> 6);
  const int lane = threadIdx.x & 63;
  const int row = wv >> 5, j0 = (wv & 31) << 6;
  unsigned long long mask = __ballot(adj[(size_t)row * 2048 + j0 + lane] > 0);
  if (lane == 0) {
    adjm[row * 64 + (j0 >> 5)]     = (unsigned)mask;
    adjm[row * 64 + (j0 >> 5) + 1] = (unsigned)(mask >> 32);
  }
}

// ---------------- Kernel B: fused conv + Wh GEMM + pack + f1/f2 ----------------
// block: 32 gemm rows = (b, n in [jg*32, jg*32+32)); 512 thr = 8 waves (2 rg x 4 cg).
// whp[b][jc 128][ct 12][lane 64][8]: lane l elem e = Wh[b][jc*16 + (l>>5)*8 + e][ct*32 + (l&31)]
__global__ __launch_bounds__(512) void gemm_wh3_kernel(const float* __restrict__ x,
                                                       const float* __restrict__ cw,
                                                       const float* __restrict__ cb,
                                                       const unsigned short* __restrict__ Wt,
                                                       const float* __restrict__ a,
                                                       unsigned short* __restrict__ whp,
                                                       float* __restrict__ f1,
                                                       float* __restrict__ f2) {
  __shared__ __align__(16) char lds[49344 + 1792 + 256];
  float* xin = (float*)lds;                                   // [12][1028], 1026 used
  unsigned short* atile = (unsigned short*)lds;               // [32][392] (after conv)
  unsigned short* wtile = (unsigned short*)(lds + 25088);     // [32][392]
  float* cws = (float*)(lds + 49344);                         // 432
  float* cbs = cws + 448;                                     // 12
  float* s1s = (float*)(lds + 49344 + 1792);                  // 32
  float* s2s = s1s + 32;                                      // 32

  const int tid = threadIdx.x;
  const int rb = blockIdx.x;
  const int b = rb >> 6, jg = rb & 63;
  const int r0 = rb << 5;
  const int w = tid >> 6, lane = tid & 63;
  const int rg = w >> 2, cg = w & 3;
  const int il = lane & 15, kg = lane >> 4;

  // stage conv weights + x tile
  if (tid < 432) cws[tid] = cw[tid];
  if (tid < 12) cbs[tid] = cb[tid];
  if (tid < 32) { s1s[tid] = 0.f; s2s[tid] = 0.f; }
  const float* xb = x + (size_t)b * 2048 * 12 * 32;
#pragma unroll
  for (int t = 0; t < 12; ++t) {
    for (int i = tid; i < 1026; i += 512) {
      const int gp = jg * 1024 + i - 1;
      float v = 0.f;
      if ((unsigned)gp < 65536u) v = xb[((size_t)(gp >> 5) * 12 + t) * 32 + (gp & 31)];
      xin[t * 1028 + i] = v;
    }
  }
  __syncthreads();

  // conv: each thread 2 p's x 12 t_o
  const int ploc = tid * 2;
  float accv0[12], accv1[12];
#pragma unroll
  for (int to = 0; to < 12; ++to) { accv0[to] = cbs[to]; accv1[to] = cbs[to]; }
#pragma unroll
  for (int ti = 0; ti < 12; ++ti) {
    const float x0 = xin[ti * 1028 + ploc];
    const float x1 = xin[ti * 1028 + ploc + 1];
    const float x2 = xin[ti * 1028 + ploc + 2];
    const float x3 = xin[ti * 1028 + ploc + 3];
#pragma unroll
    for (int to = 0; to < 12; ++to) {
      const float* wp = &cws[(to * 12 + ti) * 3];
      const float w0 = wp[0], w1 = wp[1], w2 = wp[2];
      accv0[to] += x0 * w0 + x1 * w1 + x2 * w2;
      accv1[to] += x1 * w0 + x2 * w1 + x3 * w2;
    }
  }
  __syncthreads();   // all xin reads done before atile overwrite

  // write conv out as bf16 A-tile (atile overlaps xin space)
  {
    const int row = ploc >> 5, f = ploc & 31;
    unsigned* ap32 = (unsigned*)(atile + row * 392 + f);
#pragma unroll
    for (int to = 0; to < 12; ++to) {
      const unsigned lo = f2bf(accv0[to]), hi = f2bf(accv1[to]);
      ap32[to * 16] = lo | (hi << 16);
    }
  }
  __syncthreads();

  // MFMA: 32x384 = A(32x384) @ W(384x384), waves: rg rows-16, cg cols-96
  f32x4 acc[6];
#pragma unroll
  for (int t = 0; t < 6; ++t) acc[t] = (f32x4){0.f, 0.f, 0.f, 0.f};
  const unsigned short* arow = atile + (rg * 16 + il) * 392 + kg * 8;
#pragma unroll
  for (int kk = 0; kk < 12; ++kk) {
    short8 af = *reinterpret_cast<const short8*>(arow + kk * 32);
#pragma unroll
    for (int t = 0; t < 6; ++t) {
      const int c = cg * 96 + t * 16 + il;
      short8 bf = *reinterpret_cast<const short8*>(Wt + (size_t)c * 384 + kk * 32 + kg * 8);
      acc[t] = __builtin_amdgcn_mfma_f32_16x16x32_bf16(af, bf, acc[t], 0, 0, 0);
    }
  }
  // fused f1/f2
  float p1[4] = {0.f, 0.f, 0.f, 0.f}, p2[4] = {0.f, 0.f, 0.f, 0.f};
#pragma unroll
  for (int t = 0; t < 6; ++t) {
    const int c = cg * 96 + t * 16 + il;
    const float a1v = a[c], a2v = a[384 + c];
#pragma unroll
    for (int r = 0; r < 4; ++r) { p1[r] += acc[t][r] * a1v; p2[r] += acc[t][r] * a2v; }
  }
#pragma unroll
  for (int off = 1; off < 16; off <<= 1) {
#pragma unroll
    for (int r = 0; r < 4; ++r) { p1[r] += __shfl_xor(p1[r], off); p2[r] += __shfl_xor(p2[r], off); }
  }
  if (il == 0) {
#pragma unroll
    for (int r = 0; r < 4; ++r) {
      atomicAdd(&s1s[rg * 16 + kg * 4 + r], p1[r]);
      atomicAdd(&s2s[rg * 16 + kg * 4 + r], p2[r]);
    }
  }
#pragma unroll
  for (int t = 0; t < 6; ++t)
#pragma unroll
    for (int r = 0; r < 4; ++r)
      wtile[(rg * 16 + kg * 4 + r) * 392 + cg * 96 + t * 16 + il] = f2bf(acc[t][r]);
  __syncthreads();

  // pack B-frag tiles: 24 tiles (jh 2 x ct 12) x 64 lanes; layout [b][jc][ct]
#pragma unroll
  for (int rep = 0; rep < 3; ++rep) {
    const int flat = rep * 512 + tid;
    const int tile = flat >> 6, l = flat & 63;
    const int ct = tile >> 1, jh = tile & 1;
    const int l5 = l & 31, hw2 = l >> 5;
    short8 v;
#pragma unroll
    for (int e = 0; e < 8; ++e)
      v[e] = (short)wtile[(jh * 16 + hw2 * 8 + e) * 392 + ct * 32 + l5];
    *reinterpret_cast<short8*>((char*)whp +
        ((((size_t)b * 128 + jg * 2 + jh) * 12 + ct) << 10) + l * 16) = v;
  }
  if (tid < 32) { f1[r0 + tid] = s1s[tid]; f2[r0 + tid] = s2s[tid]; }
}

// ---------------- per-batch max of f2 ----------------
__global__ __launch_bounds__(256) void f2max_kernel(const float* __restrict__ f2,
                                                    float* __restrict__ gmax) {
  __shared__ float wm[4];
  const int b = blockIdx.x;
  const int tid = threadIdx.x;
  float m = -3.0e38f;
  for (int i = tid; i < 2048; i += 256) m = fmaxf(m, f2[b * 2048 + i]);
#pragma unroll
  for (int off = 32; off; off >>= 1) m = fmaxf(m, __shfl_xor(m, off));
  if ((tid & 63) == 0) wm[tid >> 6] = m;
  __syncthreads();
  if (tid == 0) gmax[b] = fmaxf(fmaxf(wm[0], wm[1]), fmaxf(wm[2], wm[3]));
}

// ---------------- Kernel E: attention v10 ----------------
// attn8 structure with ONE rollback: raw f2 (8 KB, L1-resident) + in-loop __expf
// instead of the 64 KB e2f2 table (which thrashed L1). Keeps adj preload +
// contiguous [b][jc][ct] B-blob + depth-2 named pipeline. 2 waves/SIMD.
__global__ __launch_bounds__(256, 2) void attn10_kernel(const float* __restrict__ f1,
                                                        const float* __restrict__ f2,
                                                        const unsigned* __restrict__ adjm,
                                                        const unsigned short* __restrict__ whp,
                                                        const float* __restrict__ gmax,
                                                        float* __restrict__ out) {
  __shared__ float red[4][32][96];      // 48 KB
  __shared__ float dred[128];
  const int bi = blockIdx.x;
  const int ch = bi & 1;
  const int b  = (bi & 7) >> 1;
  const int i0 = (bi >> 3) << 5;
  const int tid = threadIdx.x;
  const int ks = tid >> 6;
  const int lane = tid & 63;
  const int l5 = lane & 31, hw = lane >> 5;
  const int hw8 = hw * 8;
  const int ig = i0 + l5;

  // adj preload: 16 words covering this lane's row, ks j-range, as named uint4s
  const uint4* ap_ = reinterpret_cast<const uint4*>(adjm + (size_t)ig * 64 + ks * 16);
  const uint4 aw0 = ap_[0], aw1 = ap_[1], aw2 = ap_[2], aw3 = ap_[3];

  // B-frag pointers: whp[b][jc][ct] layout; step's 6 frags contiguous (6 KB)
  const char* pA = (const char*)whp + ((((size_t)b * 128 + ks * 32) * 12) << 10) +
                   ch * 6144 + lane * 16;
  const char* pB = pA + 12288;
  const float* f2b = f2 + b * 2048;

  const float f1v = f1[b * 2048 + ig];
  const float gm = gmax[b];
  const float mz = f1v + gm;
  const float m  = fmaxf(mz, 0.2f * mz);     // >= true masked row max (lrelu monotone)
  const float Az = f1v - m;
  const float Bz = 0.2f * f1v - m;

  const f32x16 zero16 = {0.f,0.f,0.f,0.f,0.f,0.f,0.f,0.f,0.f,0.f,0.f,0.f,0.f,0.f,0.f,0.f};
  f32x16 acc[6];
#pragma unroll
  for (int t = 0; t < 6; ++t) acc[t] = zero16;
  float denom = 0.f;

  short8 bA0, bA1, bA2, bA3, bA4, bA5, bB0, bB1, bB2, bB3, bB4, bB5;
  float4 fA0, fA1, fB0, fB1;

#define CAT3(X, Y, Z) X##Y##Z
#define FV(S, N) CAT3(f, S, N)
#define BFV(S, N) CAT3(b, S, N)

#define LOADB(S)                                                                        \
  { BFV(S,0) = *reinterpret_cast<const short8*>(p##S);                                  \
    BFV(S,1) = *reinterpret_cast<const short8*>(p##S + 1024);                           \
    BFV(S,2) = *reinterpret_cast<const short8*>(p##S + 2048);                           \
    BFV(S,3) = *reinterpret_cast<const short8*>(p##S + 3072);                           \
    const char* p4_ = p##S + 4096;                                                      \
    BFV(S,4) = *reinterpret_cast<const short8*>(p4_);                                   \
    BFV(S,5) = *reinterpret_cast<const short8*>(p4_ + 1024);                            \
    p##S += 24576; }

#define LOADF(S, KK)                                                                    \
  { const float* fp_ = f2b + ks * 512 + (KK) * 16 + hw8;                                \
    FV(S,0) = *reinterpret_cast<const float4*>(fp_);                                    \
    FV(S,1) = *reinterpret_cast<const float4*>(fp_ + 4); }

#define PEL(GV, BIT, DST)                                                               \
  { const float z_ = Az + (GV);                                                         \
    const float e_ = fmaxf(z_, fmaf((GV), 0.2f, Bz));                                   \
    DST = ((bits_ >> (BIT)) & 1u) ? __expf(e_) : 0.f; }

#define PKBF(HI, LO) (((__float_as_uint(HI) + 0x8000u) & 0xffff0000u) |                 \
                      ((__float_as_uint(LO) + 0x8000u) >> 16))

#define STEP(S, W, SH, KK, DL)                                                          \
  { const unsigned bits_ = (W) >> ((SH) + hw8);                                         \
    const float gv0_ = FV(S,0).x, gv1_ = FV(S,0).y, gv2_ = FV(S,0).z, gv3_ = FV(S,0).w; \
    const float gv4_ = FV(S,1).x, gv5_ = FV(S,1).y, gv6_ = FV(S,1).z, gv7_ = FV(S,1).w; \
    float p0_, p1_, p2_, p3_, p4_, p5_, p6_, p7_;                                       \
    PEL(gv0_, 0, p0_)  PEL(gv1_, 1, p1_)  PEL(gv2_, 2, p2_)  PEL(gv3_, 3, p3_)          \
    PEL(gv4_, 4, p4_)  PEL(gv5_, 5, p5_)  PEL(gv6_, 6, p6_)  PEL(gv7_, 7, p7_)          \
    denom += (((p0_ + p1_) + (p2_ + p3_)) + ((p4_ + p5_) + (p6_ + p7_)));               \
    union { unsigned u[4]; short8 s8; } cc;                                             \
    cc.u[0] = PKBF(p1_, p0_); cc.u[1] = PKBF(p3_, p2_);                                 \
    cc.u[2] = PKBF(p5_, p4_); cc.u[3] = PKBF(p7_, p6_);                                 \
    acc[0] = __builtin_amdgcn_mfma_f32_32x32x16_bf16(cc.s8, BFV(S,0), acc[0], 0, 0, 0); \
    acc[1] = __builtin_amdgcn_mfma_f32_32x32x16_bf16(cc.s8, BFV(S,1), acc[1], 0, 0, 0); \
    acc[2] = __builtin_amdgcn_mfma_f32_32x32x16_bf16(cc.s8, BFV(S,2), acc[2], 0, 0, 0); \
    acc[3] = __builtin_amdgcn_mfma_f32_32x32x16_bf16(cc.s8, BFV(S,3), acc[3], 0, 0, 0); \
    acc[4] = __builtin_amdgcn_mfma_f32_32x32x16_bf16(cc.s8, BFV(S,4), acc[4], 0, 0, 0); \
    acc[5] = __builtin_amdgcn_mfma_f32_32x32x16_bf16(cc.s8, BFV(S,5), acc[5], 0, 0, 0); \
    if (DL) { LOADB(S) LOADF(S, (KK) + 2) } }

#define GROUP(AW, K0)                                                                   \
  STEP(A, AW.x, 0, (K0) + 0, 1)  STEP(B, AW.x, 16, (K0) + 1, 1)                         \
  STEP(A, AW.y, 0, (K0) + 2, 1)  STEP(B, AW.y, 16, (K0) + 3, 1)                         \
  STEP(A, AW.z, 0, (K0) + 4, 1)  STEP(B, AW.z, 16, (K0) + 5, 1)                         \
  STEP(A, AW.w, 0, (K0) + 6, 1)  STEP(B, AW.w, 16, (K0) + 7, 1)

#define GROUPL(AW, K0)                                                                  \
  STEP(A, AW.x, 0, (K0) + 0, 1)  STEP(B, AW.x, 16, (K0) + 1, 1)                         \
  STEP(A, AW.y, 0, (K0) + 2, 1)  STEP(B, AW.y, 16, (K0) + 3, 1)                         \
  STEP(A, AW.z, 0, (K0) + 4, 1)  STEP(B, AW.z, 16, (K0) + 5, 1)                         \
  STEP(A, AW.w, 0, (K0) + 6, 0)  STEP(B, AW.w, 16, (K0) + 7, 0)

  // prologue: fill both stages
  LOADB(A) LOADB(B)
  LOADF(A, 0) LOADF(B, 1)

  GROUP(aw0, 0)
  GROUP(aw1, 8)
  GROUP(aw2, 16)
  GROUPL(aw3, 24)

#undef LOADB
#undef LOADF
#undef PEL
#undef PKBF
#undef STEP
#undef GROUP
#undef GROUPL
#undef CAT3
#undef FV
#undef BFV

  // ---- epilogue: combine 4 ks accumulators via LDS, normalize, elu, store ----
  float dn = denom + __shfl_xor(denom, 32);
  if (hw == 0) dred[ks * 32 + l5] = dn;

#pragma unroll
  for (int r = 0; r < 2; ++r) {
#pragma unroll
    for (int t3 = 0; t3 < 3; ++t3) {
      const int t = r * 3 + t3;
#pragma unroll
      for (int q = 0; q < 16; ++q) {
        const int row = (q & 3) + 8 * (q >> 2) + 4 * hw;
        red[ks][row][t3 * 32 + l5] = acc[t][q];
      }
    }
    __syncthreads();
    const size_t ob = ((size_t)b * 2048 + i0) * 384 + ch * 192 + r * 96;
#pragma unroll
    for (int p = 0; p < 12; ++p) {
      const int idx = p * 256 + tid;
      const int row = idx / 96;
      const int c = idx - row * 96;
      float v = red[0][row][c] + red[1][row][c] + red[2][row][c] + red[3][row][c];
      const float d = dred[row] + dred[32 + row] + dred[64 + row] + dred[96 + row];
      v /= d;
      v = v > 0.f ? v : expm1f(v);
      out[ob + (size_t)row * 384 + c] = v;
    }
    __syncthreads();
  }
}

extern "C" void kernel_launch(void* const* d_in, const int* in_sizes, int n_in,
                              void* d_out, int out_size, void* d_ws, size_t ws_size,
                              hipStream_t stream) {
  const float* x  = (const float*)d_in[0];
  const int* adj  = (const int*)d_in[1];
  const float* W  = (const float*)d_in[2];
  const float* a  = (const float*)d_in[3];
  const float* cw = (const float*)d_in[4];
  const float* cb = (const float*)d_in[5];
  float* out = (float*)d_out;

  char* ws = (char*)d_ws;
  unsigned short* Wt  = (unsigned short*)ws; ws += (size_t)147456 * 2;   // [384][384] bf16 (T)
  unsigned short* whp = (unsigned short*)ws; ws += (size_t)3145728 * 2;  // packed B-frags [b][jc][ct]
  float* f1           = (float*)ws;          ws += (size_t)8192 * 4;
  float* f2           = (float*)ws;          ws += (size_t)8192 * 4;
  unsigned* adjm      = (unsigned*)ws;       ws += (size_t)2048 * 64 * 4;
  float* gmax         = (float*)ws;          ws += 64;

  transpose_f2b_kernel<<<dim3(12, 12), 256, 0, stream>>>(W, Wt, 384, 384);
  adjmask_kernel<<<dim3(16384), 256, 0, stream>>>(adj, adjm);
  gemm_wh3_kernel<<<dim3(256), 512, 0, stream>>>(x, cw, cb, Wt, a, whp, f1, f2);
  f2max_kernel<<<dim3(4), 256, 0, stream>>>(f2, gmax);
  attn10_kernel<<<dim3(512), 256, 0, stream>>>(f1, f2, adjm, whp, gmax, out);
}